// Round 16
// baseline (53.600 us; speedup 1.0000x reference)
//
#include <hip/hip_runtime.h>

#define NFEAT   100000
#define NBATCH  256
#define DIM     128
#define MARGIN_F 0.5f
#define FLT_BIG 3.402823466e+38f

// ---- bf16-path geometry (K1b): 625 blocks x 160 rows = 100000 exactly
#define GRIDB   625
#define RPBB    160
#define NTILEB  10                        // 16-row tiles
#define BBYTESB (RPBB * DIM * 2)          // 40 KiB bf16 staged per block

// ---- f32 fallback geometry (R13): 1250 x 80
#define GRIDF   1250
#define RPBF    80
#define NTILEF  5

typedef __bf16 bf8_t  __attribute__((ext_vector_type(8)));
typedef short  sh8_t  __attribute__((ext_vector_type(8)));
typedef float  f32x4  __attribute__((ext_vector_type(4)));

// f32 -> bf16 native cast: compiler emits v_cvt_pk_bf16_f32 pairs (RTNE).
__device__ __forceinline__ bf8_t pack8(float4 v0, float4 v1) {
  bf8_t r;
  r[0] = (__bf16)v0.x; r[1] = (__bf16)v0.y; r[2] = (__bf16)v0.z; r[3] = (__bf16)v0.w;
  r[4] = (__bf16)v1.x; r[5] = (__bf16)v1.y; r[6] = (__bf16)v1.z; r[7] = (__bf16)v1.w;
  return r;
}

// MFMA dispatch: works whether the builtin takes bf16-vectors or short-vectors
template <typename VA, typename VC>
__device__ __forceinline__ auto mfma_sel(VA a, VA b, VC c, int)
    -> decltype(__builtin_amdgcn_mfma_f32_16x16x32_bf16(a, b, c, 0, 0, 0)) {
  return __builtin_amdgcn_mfma_f32_16x16x32_bf16(a, b, c, 0, 0, 0);
}
template <typename VA, typename VC>
__device__ __forceinline__ VC mfma_sel(VA a, VA b, VC c, long) {
  return __builtin_amdgcn_mfma_f32_16x16x32_bf16(
      __builtin_bit_cast(sh8_t, a), __builtin_bit_cast(sh8_t, b), c, 0, 0, 0);
}
__device__ __forceinline__ f32x4 mfma_bf16(bf8_t a, bf8_t b, f32x4 c) {
  return mfma_sel(a, b, c, 0);
}

#if defined(__has_builtin)
#if __has_builtin(__builtin_amdgcn_global_load_lds)
#define HAVE_GLLDS 1
#endif
#endif

__device__ __forceinline__ void stage16(const char* g, char* l) {
#ifdef HAVE_GLLDS
  __builtin_amdgcn_global_load_lds(
      (const __attribute__((address_space(1))) unsigned int*)g,
      (__attribute__((address_space(3))) unsigned int*)l, 16, 0, 0);
#else
  *reinterpret_cast<float4*>(l) = *reinterpret_cast<const float4*>(g);
#endif
}

// ============================================================================
// K1a (ABLATION PROBE + real work): pure streaming f32->bf16 cast of features
// into d_ws. This is exactly m13's copy shape (77 MB moved). Its dur_us is the
// decisive diagnostic: healthy = 13-19us @ 4-6 TB/s; if it ALSO crawls at
// ~1 TB/s, the 15-round delivery cap is environmental, not kernel-structural.
// ============================================================================
__global__ __launch_bounds__(256) void feat_to_bf16(
    const float* __restrict__ src, __bf16* __restrict__ dst,
    float* __restrict__ out)
{
  if (blockIdx.x == 0 && threadIdx.x == 0) out[0] = 0.0f;  // K2 accumulates
  const int gid    = blockIdx.x * 256 + threadIdx.x;
  const int stride = gridDim.x * 256;
  const int n8     = NFEAT * DIM / 8;     // 1.6M groups of 8 elems
  for (int i = gid; i < n8; i += stride) {
    const float* p = src + (size_t)i * 8;
    float4 v0 = *reinterpret_cast<const float4*>(p);
    float4 v1 = *reinterpret_cast<const float4*>(p + 4);
    *reinterpret_cast<bf8_t*>(dst + (size_t)i * 8) = pack8(v0, v1);
  }
}

// ============================================================================
// K1b: fused GEMM + masked min/max partials, reading BF16 features from d_ws.
// Structure = R13 burst-stage barrier-once (best measured). Feature stream
// halved to 25.6MB (L2/L3-warm: K1a just wrote it); B-fragments come straight
// off ds_read_b128 -- ZERO conversion VALU for B. 625 blocks x 160 rows,
// 40 KiB LDS, 8 waves x 2 M-tiles. Swizzle: byte ^= (row&7)<<4 within the
// 256B bf16 row, applied on the DMA SOURCE (linear LDS dest, rule 21) and
// undone on the read. Partials [blk][row] contiguous (R13: transposed =
// cross-XCD write ping-pong). (512,2) cap (R6: tighter = spills).
// MFMA 16x16x32 layouts (guide §3, m89/m91-verified).
// ============================================================================
__global__ __launch_bounds__(512, 2) void triplet_partial_bf16(
    const float* __restrict__ inputs, const __bf16* __restrict__ featb,
    const int* __restrict__ targets, const int* __restrict__ flabels,
    const int* __restrict__ idx,
    float* __restrict__ ppos, float* __restrict__ pneg)
{
  __shared__ char sB[BBYTESB];         // 40 KiB bf16: 160 rows x 256B

  const int tid  = threadIdx.x;
  const int lane = tid & 63;
  const int wv   = tid >> 6;      // 0..7
  const int l15  = lane & 15;
  const int lg   = lane >> 4;     // 0..3
  const int m0   = wv * 32;
  const int blk  = blockIdx.x;
  const int rowbase = blk * RPBB;

  // ---- 1) burst-stage ALL of B (5 x 16B DMA per thread), linear LDS dest,
  // pre-swizzled global source (inverse of the read-side XOR, 256B rows).
#pragma unroll
  for (int i = 0; i < NTILEB; ++i) {
    const int p    = i * 8192 + tid * 16;     // LDS byte offset
    const int prow = p >> 8;                  // 0..159 (256B bf16 rows)
    const int scol = (p & 255) ^ ((prow & 7) << 4);
    stage16((const char*)featb + (size_t)(rowbase + prow) * 256 + scol,
            &sB[p]);
  }

  // ---- 2) A fragments (f32 inputs, cvt on the fly; <=8 float4 live)
  bf8_t afrag[2][4];
#pragma unroll
  for (int mt = 0; mt < 2; ++mt) {
    const float* ap = inputs + (m0 + mt * 16 + l15) * DIM;
    float4 v0[4], v1[4];
#pragma unroll
    for (int ks = 0; ks < 4; ++ks) {
      const int k = ks * 32 + lg * 8;
      v0[ks] = *reinterpret_cast<const float4*>(ap + k);
      v1[ks] = *reinterpret_cast<const float4*>(ap + k + 4);
    }
#pragma unroll
    for (int ks = 0; ks < 4; ++ks)
      afrag[mt][ks] = pack8(v0[ks], v1[ks]);
  }

  // ---- 3) labels + packed row metadata
  int lab[NTILEB];
#pragma unroll
  for (int t = 0; t < NTILEB; ++t)
    lab[t] = flabels[rowbase + t * 16 + l15];

  int meta[2][4];
#pragma unroll
  for (int mt = 0; mt < 2; ++mt)
#pragma unroll
    for (int rr = 0; rr < 4; ++rr) {
      const int row = m0 + mt * 16 + lg * 4 + rr;
      meta[mt][rr] = (idx[row] << 10) | targets[row];   // lab<1000: 10 bits
    }

  float minpos[2][4], maxneg[2][4];
#pragma unroll
  for (int mt = 0; mt < 2; ++mt)
#pragma unroll
    for (int rr = 0; rr < 4; ++rr) { minpos[mt][rr] = FLT_BIG; maxneg[mt][rr] = -FLT_BIG; }

  __syncthreads();   // the ONE drain: all DMAs landed, B fully in LDS

  // ---- 4) barrier-free compute: 10 tiles from LDS, bfrag = raw ds_read_b128
  const int swz = (l15 & 7) << 4;
#pragma unroll
  for (int t = 0; t < NTILEB; ++t) {
    const char* rbase = &sB[(t * 16 + l15) * 256];
    const int   j     = rowbase + t * 16 + l15;
    const int   labj  = lab[t];

    f32x4 acc0 = {0.f, 0.f, 0.f, 0.f};
    f32x4 acc1 = {0.f, 0.f, 0.f, 0.f};
#pragma unroll
    for (int ks = 0; ks < 4; ++ks) {
      const int o = (ks * 64 + lg * 16) ^ swz;
      bf8_t bf = *reinterpret_cast<const bf8_t*>(rbase + o);
      acc0 = mfma_bf16(afrag[0][ks], bf, acc0);
      acc1 = mfma_bf16(afrag[1][ks], bf, acc1);
    }

#pragma unroll
    for (int rr = 0; rr < 4; ++rr) {
      {
        const int   m    = meta[0][rr];
        const bool same  = (labj == (m & 1023));
        const bool self  = (j == (m >> 10));
        minpos[0][rr] = fminf(minpos[0][rr], (same && !self) ? acc0[rr] : FLT_BIG);
        maxneg[0][rr] = fmaxf(maxneg[0][rr], same ? -FLT_BIG : acc0[rr]);
      }
      {
        const int   m    = meta[1][rr];
        const bool same  = (labj == (m & 1023));
        const bool self  = (j == (m >> 10));
        minpos[1][rr] = fminf(minpos[1][rr], (same && !self) ? acc1[rr] : FLT_BIG);
        maxneg[1][rr] = fmaxf(maxneg[1][rr], same ? -FLT_BIG : acc1[rr]);
      }
    }
  }

  // ---- 5) reduce across the 16-lane col group; contiguous [blk][row] write
#pragma unroll
  for (int mt = 0; mt < 2; ++mt)
#pragma unroll
    for (int rr = 0; rr < 4; ++rr) {
      float mp = minpos[mt][rr], mn = maxneg[mt][rr];
#pragma unroll
      for (int m = 1; m < 16; m <<= 1) {
        mp = fminf(mp, __shfl_xor(mp, m, 64));
        mn = fmaxf(mn, __shfl_xor(mn, m, 64));
      }
      if (l15 == 0) {
        const int row = m0 + mt * 16 + lg * 4 + rr;
        ppos[blk * NBATCH + row] = mp;
        pneg[blk * NBATCH + row] = mn;
      }
    }
}

// ============================================================================
// Fallback (ws too small): R13 f32 monolith, 1250 x 80, known-good 43us path.
// ============================================================================
__global__ __launch_bounds__(512, 2) void triplet_partial_f32(
    const float* __restrict__ inputs, const float* __restrict__ features,
    const int* __restrict__ targets, const int* __restrict__ flabels,
    const int* __restrict__ idx,
    float* __restrict__ ppos, float* __restrict__ pneg,
    float* __restrict__ out)
{
  __shared__ char sB[RPBF * DIM * 4];

  const int tid  = threadIdx.x;
  const int lane = tid & 63;
  const int wv   = tid >> 6;
  const int l15  = lane & 15;
  const int lg   = lane >> 4;
  const int m0   = wv * 32;
  const int blk  = blockIdx.x;
  const int rowbase = blk * RPBF;

  if (blk == 0 && tid == 0) out[0] = 0.0f;

#pragma unroll
  for (int i = 0; i < NTILEF; ++i) {
    const int p    = i * 8192 + tid * 16;
    const int prow = p >> 9;
    const int scol = (p & 511) ^ ((prow & 7) << 4);
    stage16((const char*)features + (size_t)(rowbase + prow) * 512 + scol, &sB[p]);
  }

  bf8_t afrag[2][4];
#pragma unroll
  for (int mt = 0; mt < 2; ++mt) {
    const float* ap = inputs + (m0 + mt * 16 + l15) * DIM;
    float4 v0[4], v1[4];
#pragma unroll
    for (int ks = 0; ks < 4; ++ks) {
      const int k = ks * 32 + lg * 8;
      v0[ks] = *reinterpret_cast<const float4*>(ap + k);
      v1[ks] = *reinterpret_cast<const float4*>(ap + k + 4);
    }
#pragma unroll
    for (int ks = 0; ks < 4; ++ks)
      afrag[mt][ks] = pack8(v0[ks], v1[ks]);
  }

  int lab[NTILEF];
#pragma unroll
  for (int t = 0; t < NTILEF; ++t)
    lab[t] = flabels[rowbase + t * 16 + l15];

  int meta[2][4];
#pragma unroll
  for (int mt = 0; mt < 2; ++mt)
#pragma unroll
    for (int rr = 0; rr < 4; ++rr) {
      const int row = m0 + mt * 16 + lg * 4 + rr;
      meta[mt][rr] = (idx[row] << 10) | targets[row];
    }

  float minpos[2][4], maxneg[2][4];
#pragma unroll
  for (int mt = 0; mt < 2; ++mt)
#pragma unroll
    for (int rr = 0; rr < 4; ++rr) { minpos[mt][rr] = FLT_BIG; maxneg[mt][rr] = -FLT_BIG; }

  __syncthreads();

  const int swz = (l15 & 7) << 4;
#pragma unroll
  for (int t = 0; t < NTILEF; ++t) {
    const char* rbase = &sB[(t * 16 + l15) * 512];
    const int   j     = rowbase + t * 16 + l15;
    const int   labj  = lab[t];

    f32x4 acc0 = {0.f, 0.f, 0.f, 0.f};
    f32x4 acc1 = {0.f, 0.f, 0.f, 0.f};
#pragma unroll
    for (int ks = 0; ks < 4; ++ks) {
      const int o = ks * 128 + lg * 32;
      float4 v0 = *reinterpret_cast<const float4*>(rbase + ((o)      ^ swz));
      float4 v1 = *reinterpret_cast<const float4*>(rbase + ((o + 16) ^ swz));
      bf8_t bf = pack8(v0, v1);
      acc0 = mfma_bf16(afrag[0][ks], bf, acc0);
      acc1 = mfma_bf16(afrag[1][ks], bf, acc1);
    }
#pragma unroll
    for (int rr = 0; rr < 4; ++rr) {
      {
        const int  m = meta[0][rr];
        const bool same = (labj == (m & 1023));
        const bool self = (j == (m >> 10));
        minpos[0][rr] = fminf(minpos[0][rr], (same && !self) ? acc0[rr] : FLT_BIG);
        maxneg[0][rr] = fmaxf(maxneg[0][rr], same ? -FLT_BIG : acc0[rr]);
      }
      {
        const int  m = meta[1][rr];
        const bool same = (labj == (m & 1023));
        const bool self = (j == (m >> 10));
        minpos[1][rr] = fminf(minpos[1][rr], (same && !self) ? acc1[rr] : FLT_BIG);
        maxneg[1][rr] = fmaxf(maxneg[1][rr], same ? -FLT_BIG : acc1[rr]);
      }
    }
  }

#pragma unroll
  for (int mt = 0; mt < 2; ++mt)
#pragma unroll
    for (int rr = 0; rr < 4; ++rr) {
      float mp = minpos[mt][rr], mn = maxneg[mt][rr];
#pragma unroll
      for (int m = 1; m < 16; m <<= 1) {
        mp = fminf(mp, __shfl_xor(mp, m, 64));
        mn = fmaxf(mn, __shfl_xor(mn, m, 64));
      }
      if (l15 == 0) {
        const int row = m0 + mt * 16 + lg * 4 + rr;
        ppos[blk * NBATCH + row] = mp;
        pneg[blk * NBATCH + row] = mn;
      }
    }
}

// Kernel 2: one block per batch row; fold nblk partials, hinge, atomic mean.
__global__ __launch_bounds__(256) void triplet_reduce(
    const float* __restrict__ ppos, const float* __restrict__ pneg,
    float* __restrict__ out, int nblk)
{
  const int r = blockIdx.x;
  const int t = threadIdx.x;
  float mp = FLT_BIG, mn = -FLT_BIG;
  for (int b = t; b < nblk; b += 256) {
    mp = fminf(mp, ppos[b * NBATCH + r]);
    mn = fmaxf(mn, pneg[b * NBATCH + r]);
  }
#pragma unroll
  for (int m = 1; m < 64; m <<= 1) {
    mp = fminf(mp, __shfl_xor(mp, m, 64));
    mn = fmaxf(mn, __shfl_xor(mn, m, 64));
  }
  __shared__ float smp[4], smn[4];
  if ((t & 63) == 0) { smp[t >> 6] = mp; smn[t >> 6] = mn; }
  __syncthreads();
  if (t == 0) {
    mp = fminf(fminf(smp[0], smp[1]), fminf(smp[2], smp[3]));
    mn = fmaxf(fmaxf(smn[0], smn[1]), fmaxf(smn[2], smn[3]));
    float loss = mn - mp + MARGIN_F;
    loss = loss > 0.f ? loss : 0.f;
    atomicAdd(out, loss * (1.0f / NBATCH));
  }
}

extern "C" void kernel_launch(void* const* d_in, const int* in_sizes, int n_in,
                              void* d_out, int out_size, void* d_ws, size_t ws_size,
                              hipStream_t stream) {
  const float* inputs   = (const float*)d_in[0];
  const float* features = (const float*)d_in[1];
  const int*   targets  = (const int*)d_in[2];
  const int*   flabels  = (const int*)d_in[3];
  const int*   idx      = (const int*)d_in[4];
  float* out = (float*)d_out;

  const size_t featb_bytes = (size_t)NFEAT * DIM * 2;           // 25.6 MB
  const size_t part_bytes  = (size_t)GRIDB * NBATCH * 4;        // 640 KB each

  if (ws_size >= featb_bytes + 2 * part_bytes) {
    __bf16* featb = (__bf16*)d_ws;
    float*  ppos  = (float*)((char*)d_ws + featb_bytes);
    float*  pneg  = ppos + (size_t)GRIDB * NBATCH;
    feat_to_bf16<<<2048, 256, 0, stream>>>(features, featb, out);
    triplet_partial_bf16<<<GRIDB, 512, 0, stream>>>(inputs, featb, targets,
                                                    flabels, idx, ppos, pneg);
    triplet_reduce<<<NBATCH, 256, 0, stream>>>(ppos, pneg, out, GRIDB);
  } else {
    float* ppos = (float*)d_ws;                       // [GRIDF][256]
    float* pneg = ppos + (size_t)GRIDF * NBATCH;      // ~2.56 MB total
    triplet_partial_f32<<<GRIDF, 512, 0, stream>>>(inputs, features, targets,
                                                   flabels, idx, ppos, pneg, out);
    triplet_reduce<<<NBATCH, 256, 0, stream>>>(ppos, pneg, out, GRIDF);
  }
}